// Round 8
// baseline (392.273 us; speedup 1.0000x reference)
//
#include <hip/hip_runtime.h>
#include <math.h>

#define DEVI __device__ __forceinline__

typedef __attribute__((ext_vector_type(4))) float f32x4;
typedef __attribute__((ext_vector_type(8))) short bf16x8;

// ---------- helpers ----------
DEVI short f2bf(float f) {                    // f32 -> bf16 (RNE)
    union { float f; unsigned u; } v; v.f = f;
    unsigned r = v.u + 0x7fffu + ((v.u >> 16) & 1u);
    return (short)(r >> 16);
}
DEVI float bf2f(short s) {
    union { unsigned u; float f; } v; v.u = ((unsigned)(unsigned short)s) << 16;
    return v.f;
}

DEVI f32x4 mfma16(bf16x8 a, bf16x8 b, f32x4 c) {
    return __builtin_amdgcn_mfma_f32_16x16x32_bf16(a, b, c, 0, 0, 0);
}

DEVI void gload16(const short* g, short* l) {  // async global->LDS, 16B/lane
    __builtin_amdgcn_global_load_lds((__attribute__((address_space(1))) void*)(g),
                                     (__attribute__((address_space(3))) void*)(l),
                                     16, 0, 0);
}

// ---------- elementwise f32 -> bf16 ----------
__global__ void k_cvt_bf16(const float* __restrict__ in, short* __restrict__ out, int n) {
    int i = (blockIdx.x * blockDim.x + threadIdx.x) * 4;
    if (i >= n) return;
    float4 v = *(const float4*)(in + i);
    short4 o;
    o.x = f2bf(v.x); o.y = f2bf(v.y); o.z = f2bf(v.z); o.w = f2bf(v.w);
    *(short4*)(out + i) = o;
}

// ---------- transpose + convert: in f32 [R][C] -> out bf16 rows (c*rmul+radd), zero pad ----------
__global__ void k_transpose_cvt(const float* __restrict__ in, short* __restrict__ out,
                                int R, int C, int Rpad, int Cpad, int rmul, int radd) {
    __shared__ float tile[32][33];
    int c0 = blockIdx.x * 32;   // C-dim (out rows)
    int r0 = blockIdx.y * 32;   // R-dim (out cols)
    int tx = threadIdx.x & 31, ty = threadIdx.x >> 5;   // ty in [0,8)
#pragma unroll
    for (int i = 0; i < 4; i++) {
        int r = r0 + ty + 8 * i, c = c0 + tx;
        tile[ty + 8 * i][tx] = (r < R && c < C) ? in[(size_t)r * C + c] : 0.0f;
    }
    __syncthreads();
#pragma unroll
    for (int i = 0; i < 4; i++) {
        int oc = c0 + ty + 8 * i;   // out row (pre-interleave)
        int orr = r0 + tx;          // out col
        if (oc < Cpad && orr < Rpad)
            out[(size_t)(oc * rmul + radd) * Rpad + orr] = f2bf(tile[tx][ty + 8 * i]);
    }
}

// ---------- RoPE freq tables (f64 for reference fidelity) ----------
__global__ void k_freqs(float* __restrict__ cost, float* __restrict__ sint) {
    int i = blockIdx.x * blockDim.x + threadIdx.x;   // [0, 2048*32)
    int s = i >> 5, j = i & 31;
    double inv = pow(10000.0, -(double)j / 32.0);
    double f = (double)s * inv;
    cost[i] = (float)cos(f);
    sint[i] = (float)sin(f);
}

// ---------- GEMM 128x128x32 (2-phase, for N=1024 shapes) ----------
// EPI: 0 = f32 out, 1 = bf16 out
template <int EPI>
__launch_bounds__(256)
__global__ void k_gemm128(const short* __restrict__ A, const short* __restrict__ BT,
                          void* __restrict__ Cv, int M, int N, int K) {
    __shared__ __align__(16) short As[128 * 32];
    __shared__ __align__(16) short Bs[128 * 32];
    const int t = threadIdx.x;
    const int w = t >> 6;
    const int lane = t & 63;
    const int lr = lane & 15, lg = lane >> 4;
    const int m0 = blockIdx.x * 128, n0 = blockIdx.y * 128;
    const int wr = (w >> 1) * 64, wc = (w & 1) * 64;

    f32x4 acc[4][4];
#pragma unroll
    for (int m = 0; m < 4; m++)
#pragma unroll
        for (int n = 0; n < 4; n++)
            acc[m][n] = (f32x4){0.f, 0.f, 0.f, 0.f};

    const int nk = K >> 5;
    for (int kt = 0; kt < nk; kt++) {
        const int k0 = kt << 5;
#pragma unroll
        for (int j = 0; j < 2; j++) {
            int c = t + (j << 8);
            int row = c >> 2, col = (c & 3) << 3;
            gload16(A + (size_t)(m0 + row) * K + k0 + col,
                    As + (size_t)(w * 64 + (j << 8)) * 8);
            gload16(BT + (size_t)(n0 + row) * K + k0 + col,
                    Bs + (size_t)(w * 64 + (j << 8)) * 8);
        }
        __syncthreads();
        bf16x8 af[4], bfr[4];
#pragma unroll
        for (int m = 0; m < 4; m++)
            af[m] = *(const bf16x8*)&As[(wr + m * 16 + lr) * 32 + lg * 8];
#pragma unroll
        for (int n = 0; n < 4; n++)
            bfr[n] = *(const bf16x8*)&Bs[(wc + n * 16 + lr) * 32 + lg * 8];
#pragma unroll
        for (int m = 0; m < 4; m++)
#pragma unroll
            for (int n = 0; n < 4; n++)
                acc[m][n] = mfma16(af[m], bfr[n], acc[m][n]);
        __syncthreads();
    }
#pragma unroll
    for (int m = 0; m < 4; m++)
#pragma unroll
        for (int n = 0; n < 4; n++) {
            int row = m0 + wr + m * 16 + lg * 4;
            int col = n0 + wc + n * 16 + lr;
#pragma unroll
            for (int i = 0; i < 4; i++) {
                if (EPI == 1)
                    ((short*)Cv)[(size_t)(row + i) * N + col] = f2bf(acc[m][n][i]);
                else
                    ((float*)Cv)[(size_t)(row + i) * N + col] = acc[m][n][i];
            }
        }
}

// ---------- GEMM 256x256x64, 8-wave, 4-phase/K-tile with counted vmcnt (T2+T3+T4+T5) ----------
// EPI: 1 = bf16 out (stride Nout); 2 = SwiGLU-interleaved (B rows alternate up/gate,
//      j = col/2, w = (u*s_u[j]) * silu(g*s_v[j]*32), bf16 out stride Nout, guard j<Nout).
// LDS: As/Bs [2 dbuf][2 half][128x64] bf16, XOR-swizzled (cg ^ (row&7)) both sides.
// Schedule per K-tile t (buf p=t&1): P0 reads A(mh0)+B(nh0), stages A-h0(t+1)->p^1;
// P1 reads B(nh1), stages A-h1(t+1); P2 reads A(mh1), stages B-h0(t+2)->p;
// P3 stages B-h1(t+2), vmcnt(4) before tile-end barrier. Each slot restaged >=1 barrier
// after its last reader. R7: raw s_barrier only (no sched_barrier pinning — m141 lesson);
// sched_barrier(0) kept ONLY after the vmcnt asm.
template <int EPI>
__launch_bounds__(512)
__global__ void k_gemm256(const short* __restrict__ A, const short* __restrict__ BT,
                          void* __restrict__ Cv, int M, int K, int Nout,
                          const float* __restrict__ s_u, const float* __restrict__ s_v) {
    __shared__ __align__(16) short As[2][2][8192];
    __shared__ __align__(16) short Bs[2][2][8192];
    const int t = threadIdx.x;
    const int w = t >> 6, lane = t & 63;
    const int lr = lane & 15, lg = lane >> 4;
    const int nwg = gridDim.x;
    const int wg = ((int)blockIdx.x & 7) * (nwg >> 3) + ((int)blockIdx.x >> 3);
    const int MT = M >> 8;
    const int m0 = (wg % MT) << 8, n0 = (wg / MT) << 8;
    const int wr = (w >> 2) << 7;        // 0 / 128
    const int wc = (w & 3) << 6;         // 0 / 64 / 128 / 192
    const int nt = K >> 6;
    const int hhA = wr >> 7;
    const int hhB = wc >> 7;
    const int nbase = wc & 64;

    // staging geometry: half-tile = 128 rows x 64 cols bf16 = 16KB = 512 thr x 2 x 16B
    const int srow0 = t >> 3,          scg0 = t & 7;
    const int srow1 = (t + 512) >> 3,  scg1 = t & 7;
    const int ssc0 = ((scg0 ^ (srow0 & 7)) << 3);
    const int ssc1 = ((scg1 ^ (srow1 & 7)) << 3);
    const int dst0 = (w * 64) * 8;
    const int dst1 = (512 + w * 64) * 8;

#define STAGE_A(b, hh, kt) {                                                          \
    int k0_ = ((kt) < nt ? (kt) : nt - 1) << 6;                                       \
    gload16(A + (size_t)(m0 + (hh) * 128 + srow0) * K + k0_ + ssc0, &As[b][hh][dst0]);\
    gload16(A + (size_t)(m0 + (hh) * 128 + srow1) * K + k0_ + ssc1, &As[b][hh][dst1]);}
#define STAGE_B(b, hh, kt) {                                                          \
    int k0_ = ((kt) < nt ? (kt) : nt - 1) << 6;                                       \
    gload16(BT + (size_t)(n0 + (hh) * 128 + srow0) * K + k0_ + ssc0, &Bs[b][hh][dst0]);\
    gload16(BT + (size_t)(n0 + (hh) * 128 + srow1) * K + k0_ + ssc1, &Bs[b][hh][dst1]);}
#define LDA(dst, b, mh) {                                                             \
    _Pragma("unroll") for (int m_ = 0; m_ < 4; m_++)                                  \
    _Pragma("unroll") for (int ks_ = 0; ks_ < 2; ks_++) {                             \
        int rml = (mh) * 64 + m_ * 16 + lr;                                           \
        int cg = ((ks_ << 2) + lg) ^ (rml & 7);                                       \
        dst[m_ * 2 + ks_] = *(const bf16x8*)&As[b][hhA][rml * 64 + (cg << 3)]; } }
#define LDB(dst, b, nh) {                                                             \
    _Pragma("unroll") for (int n_ = 0; n_ < 2; n_++)                                  \
    _Pragma("unroll") for (int ks_ = 0; ks_ < 2; ks_++) {                             \
        int rnl = nbase + (nh) * 32 + n_ * 16 + lr;                                   \
        int cg = ((ks_ << 2) + lg) ^ (rnl & 7);                                       \
        dst[n_ * 2 + ks_] = *(const bf16x8*)&Bs[b][hhB][rnl * 64 + (cg << 3)]; } }
#define QUAD(MB, NB, AF, BF) {                                                        \
    __builtin_amdgcn_s_setprio(1);                                                    \
    _Pragma("unroll") for (int m_ = 0; m_ < 4; m_++)                                  \
    _Pragma("unroll") for (int n_ = 0; n_ < 2; n_++) {                                \
        acc[(MB) + m_][(NB) + n_] = mfma16(AF[m_ * 2],     BF[n_ * 2],     acc[(MB) + m_][(NB) + n_]); \
        acc[(MB) + m_][(NB) + n_] = mfma16(AF[m_ * 2 + 1], BF[n_ * 2 + 1], acc[(MB) + m_][(NB) + n_]); } \
    __builtin_amdgcn_s_setprio(0); }
#define SBAR { __builtin_amdgcn_s_barrier(); }

    f32x4 acc[8][4];
#pragma unroll
    for (int m = 0; m < 8; m++)
#pragma unroll
        for (int n = 0; n < 4; n++)
            acc[m][n] = (f32x4){0.f, 0.f, 0.f, 0.f};
    bf16x8 af[8], bfr0[4], bfr1[4];

    // prologue: A(0), B(0), B(1)  (12 loads/thread); wait for A(0)+B(0)
    STAGE_A(0, 0, 0) STAGE_A(0, 1, 0)
    STAGE_B(0, 0, 0) STAGE_B(0, 1, 0)
    STAGE_B(1, 0, 1) STAGE_B(1, 1, 1)
    asm volatile("s_waitcnt vmcnt(4)" ::: "memory");
    __builtin_amdgcn_sched_barrier(0);
    SBAR

    for (int kt = 0; kt < nt; kt++) {
        const int p = kt & 1;
        // P0
        LDA(af, p, 0) LDB(bfr0, p, 0)
        STAGE_A(p ^ 1, 0, kt + 1)
        SBAR
        QUAD(0, 0, af, bfr0)
        SBAR
        // P1
        LDB(bfr1, p, 1)
        STAGE_A(p ^ 1, 1, kt + 1)
        SBAR
        QUAD(0, 2, af, bfr1)
        SBAR
        // P2
        LDA(af, p, 1)
        STAGE_B(p, 0, kt + 2)
        SBAR
        QUAD(4, 2, af, bfr1)
        SBAR
        // P3
        STAGE_B(p, 1, kt + 2)
        SBAR
        QUAD(4, 0, af, bfr0)
        asm volatile("s_waitcnt vmcnt(4)" ::: "memory");
        __builtin_amdgcn_sched_barrier(0);
        SBAR
    }

    if (EPI == 2) {
#pragma unroll
        for (int m = 0; m < 8; m++)
#pragma unroll
            for (int n = 0; n < 4; n++) {
                int col = n0 + wc + n * 16 + lr;
                int j = col >> 1;
                int jc = j < 2730 ? j : 2729;
                float su = s_u[jc], sg = s_v[jc] * 32.0f;
#pragma unroll
                for (int i = 0; i < 4; i++) {
                    int row = m0 + wr + m * 16 + lg * 4 + i;
                    float own = acc[m][n][i];
                    float oth = __shfl_xor(own, 1, 64);
                    float u = (lr & 1) ? oth : own;
                    float g = (lr & 1) ? own : oth;
                    float uu = u * su, vv = g * sg;
                    float wv = uu * vv / (1.0f + expf(-vv));
                    if (!(lr & 1) && j < Nout)
                        ((short*)Cv)[(size_t)row * Nout + j] = f2bf(wv);
                }
            }
    } else {
#pragma unroll
        for (int m = 0; m < 8; m++)
#pragma unroll
            for (int n = 0; n < 4; n++) {
                int col = n0 + wc + n * 16 + lr;
#pragma unroll
                for (int i = 0; i < 4; i++) {
                    int row = m0 + wr + m * 16 + lg * 4 + i;
                    ((short*)Cv)[(size_t)row * Nout + col] = f2bf(acc[m][n][i]);
                }
            }
    }
#undef STAGE_A
#undef STAGE_B
#undef LDA
#undef LDB
#undef QUAD
#undef SBAR
}

// ---------- RoPE + cosine_norm for q,k. qkvb bf16 [4096][3072] -> qn,kn bf16 [B][H][S][64] ----------
__global__ void k_rope(const short* __restrict__ qkvb, const float* __restrict__ cost,
                       const float* __restrict__ sint, const float* __restrict__ sqk,
                       short* __restrict__ qn, short* __restrict__ kn) {
    int wid = blockIdx.x * 4 + (threadIdx.x >> 6);   // [0, 65536)
    int lane = threadIdx.x & 63;
    int h = wid & 15;
    int s = (wid >> 4) & 2047;
    int b = wid >> 15;
    int row = b * 2048 + s;
    int j = lane & 31;
    float cs = cost[s * 32 + j];
    float sn = sint[s * 32 + j];
    float eff = sqk[h * 64 + lane] * 32.0f;          // s_qk * sqrt(DIM)
    size_t inbase = (size_t)row * 3072 + h * 64 + lane;
    size_t outbase = ((size_t)(b * 16 + h) * 2048 + s) * 64 + lane;
    {   // q  (extra *8 = sqrt(HD) logit scale folded in)
        float v = bf2f(qkvb[inbase]);
        float vp = __shfl_xor(v, 32, 64);
        float vr = (lane < 32) ? v * cs - vp * sn : v * cs + vp * sn;
        float ss = vr * vr;
#pragma unroll
        for (int o = 1; o < 64; o <<= 1) ss += __shfl_xor(ss, o, 64);
        float sc = eff * 8.0f / fmaxf(sqrtf(ss), 1e-6f);
        qn[outbase] = f2bf(vr * sc);
    }
    {   // k
        float v = bf2f(qkvb[inbase + 1024]);
        float vp = __shfl_xor(v, 32, 64);
        float vr = (lane < 32) ? v * cs - vp * sn : v * cs + vp * sn;
        float ss = vr * vr;
#pragma unroll
        for (int o = 1; o < 64; o <<= 1) ss += __shfl_xor(ss, o, 64);
        float sc = eff / fmaxf(sqrtf(ss), 1e-6f);
        kn[outbase] = f2bf(vr * sc);
    }
}

// ---------- V transpose: qkvb v-part bf16 -> vt bf16 [B][H][64][2048] ----------
__global__ void k_vtrans(const short* __restrict__ qkvb, short* __restrict__ vt) {
    __shared__ short tile[64][72];
    int blk = blockIdx.x;
    int st = blk & 31, h = (blk >> 5) & 15, b = blk >> 9;
    int s0 = st * 64;
    int t = threadIdx.x;
    int sl = t >> 2, c0 = (t & 3) * 16;
    const short* src = qkvb + (size_t)(b * 2048 + s0 + sl) * 3072 + 2048 + h * 64 + c0;
    bf16x8 a0 = *(const bf16x8*)src;
    bf16x8 a1 = *(const bf16x8*)(src + 8);
#pragma unroll
    for (int jj = 0; jj < 8; jj++) { tile[sl][c0 + jj] = a0[jj]; tile[sl][c0 + 8 + jj] = a1[jj]; }
    __syncthreads();
    int hd = t >> 2, sc = (t & 3) * 16;
    bf16x8 p0, p1;
#pragma unroll
    for (int jj = 0; jj < 8; jj++) { p0[jj] = tile[sc + jj][hd]; p1[jj] = tile[sc + 8 + jj][hd]; }
    size_t obase = ((size_t)((b * 16 + h) * 64 + hd)) * 2048 + s0 + sc;
    *(bf16x8*)&vt[obase] = p0;
    *(bf16x8*)&vt[obase + 8] = p1;
}

// ---------- flash attention (causal), static-max softmax, split-K x2, XCD-binned ----------
__launch_bounds__(512)
__global__ void k_attn(const short* __restrict__ qn, const short* __restrict__ kn,
                       const short* __restrict__ vt, short* __restrict__ opart,
                       float* __restrict__ lsump) {
    __shared__ __align__(16) short Ks[2][64 * 64];   // 2 x 8 KB
    __shared__ __align__(16) short Vs[2][64 * 64];   // 2 x 8 KB
    __shared__ __align__(16) short Ps[8][32 * 64];   // 8 x 4 KB
    const int t = threadIdx.x;
    const int w = t >> 6, lane = t & 63;
    const int bid = blockIdx.x;
    const int xcd = bid & 7, kk_ = bid >> 3;
    const int bhg = xcd + ((kk_ >> 4) << 3);         // 0..31
    const int xi = kk_ & 15;
    const int qb = 7 - (xi >> 1), hf = xi & 1;
    const int h = bhg & 15, b = bhg >> 4;
    const int bh = b * 16 + h;
    const int qw = qb * 256 + w * 32;
    const int lr = lane & 15, lg = lane >> 4;
    const short* Qb = qn + (size_t)bh * 2048 * 64;
    const short* Kb = kn + (size_t)bh * 2048 * 64;
    const short* Vb = vt + (size_t)bh * 64 * 2048;
    char* pwc = (char*)&Ps[w][0];

    bf16x8 qf[2][2];
#pragma unroll
    for (int mi = 0; mi < 2; mi++)
#pragma unroll
        for (int kk = 0; kk < 2; kk++)
            qf[mi][kk] = *(const bf16x8*)&Qb[(size_t)(qw + mi * 16 + lr) * 64 + kk * 32 + lg * 8];

    f32x4 oacc[2][4];
#pragma unroll
    for (int mi = 0; mi < 2; mi++)
#pragma unroll
        for (int ct = 0; ct < 4; ct++) oacc[mi][ct] = (f32x4){0.f, 0.f, 0.f, 0.f};
    float psum[2][4];
#pragma unroll
    for (int mi = 0; mi < 2; mi++)
#pragma unroll
        for (int i = 0; i < 4; i++) psum[mi][i] = 0.0f;

    const int ktn = 2 * qb + 2;
    const int kt0 = hf * ktn, kt1 = kt0 + ktn;

#define STAGE_KV(bi, kbase)                                                          \
    {                                                                                \
        int row = w * 8 + (lane >> 3);                                               \
        int scol = (lane & 7) ^ (row & 7);                                           \
        gload16(Kb + (size_t)((kbase) + row) * 64 + scol * 8,                        \
                &Ks[bi][(w * 8) * 64]);                                              \
        gload16(Vb + (size_t)row * 2048 + (kbase) + scol * 8,                        \
                &Vs[bi][(w * 8) * 64]);                                              \
    }

    STAGE_KV(0, kt0 << 6);

    for (int kt = kt0; kt < kt1; kt++) {
        const int kbase = kt << 6;
        const int cur = (kt - kt0) & 1;
        __syncthreads();                      // drains vmcnt -> buf cur resident
        if (kt + 1 < kt1) STAGE_KV(cur ^ 1, (kt + 1) << 6);

        bf16x8 kf[4][2];
#pragma unroll
        for (int ni = 0; ni < 4; ni++)
#pragma unroll
            for (int kk = 0; kk < 2; kk++) {
                int row = ni * 16 + lr;
                kf[ni][kk] = *(const bf16x8*)&Ks[cur][row * 64 + (((kk * 4 + lg) ^ (row & 7)) << 3)];
            }
        f32x4 sv[2][4];
#pragma unroll
        for (int mi = 0; mi < 2; mi++)
#pragma unroll
            for (int ni = 0; ni < 4; ni++) {
                f32x4 s = (f32x4){0.f, 0.f, 0.f, 0.f};
                s = mfma16(qf[mi][0], kf[ni][0], s);
                s = mfma16(qf[mi][1], kf[ni][1], s);
                sv[mi][ni] = s;
            }
        if (kbase + 63 > qw) {
#pragma unroll
            for (int mi = 0; mi < 2; mi++)
#pragma unroll
                for (int ni = 0; ni < 4; ni++)
#pragma unroll
                    for (int i = 0; i < 4; i++) {
                        int qg = qw + mi * 16 + lg * 4 + i;
                        int kg = kbase + ni * 16 + lr;
                        if (kg > qg) sv[mi][ni][i] = -3.0e38f;
                    }
        }
#pragma unroll
        for (int mi = 0; mi < 2; mi++) {
#pragma unroll
            for (int ni = 0; ni < 4; ni++)
#pragma unroll
                for (int i = 0; i < 4; i++) {
                    float p = exp2f((sv[mi][ni][i] - 9.0f) * 1.44269504f);
                    sv[mi][ni][i] = p;
                    psum[mi][i] += p;
                }
#pragma unroll
            for (int ni = 0; ni < 4; ni++)
#pragma unroll
                for (int i = 0; i < 4; i++) {
                    int row = mi * 16 + lg * 4 + i;
                    int col = ni * 16 + lr;
                    unsigned off = (unsigned)(row * 128 + col * 2) ^ ((unsigned)(row & 7) << 4);
                    *(short*)(pwc + off) = f2bf(sv[mi][ni][i]);
                }
        }
        bf16x8 pa[2][2];
#pragma unroll
        for (int mi = 0; mi < 2; mi++)
#pragma unroll
            for (int kk = 0; kk < 2; kk++) {
                int row = mi * 16 + lr;
                unsigned off = (unsigned)(row * 128 + kk * 64 + lg * 16) ^ ((unsigned)(row & 7) << 4);
                pa[mi][kk] = *(const bf16x8*)(pwc + off);
            }
        bf16x8 vf[4][2];
#pragma unroll
        for (int ct = 0; ct < 4; ct++)
#pragma unroll
            for (int kk = 0; kk < 2; kk++) {
                int row = ct * 16 + lr;
                vf[ct][kk] = *(const bf16x8*)&Vs[cur][row * 64 + (((kk * 4 + lg) ^ (row & 7)) << 3)];
            }
#pragma unroll
        for (int mi = 0; mi < 2; mi++)
#pragma unroll
            for (int ct = 0; ct < 4; ct++) {
                oacc[mi][ct] = mfma16(pa[mi][0], vf[ct][0], oacc[mi][ct]);
                oacc[mi][ct] = mfma16(pa[mi][1], vf[ct][1], oacc[mi][ct]);
            }
    }
#undef STAGE_KV

#pragma unroll
    for (int o = 1; o < 16; o <<= 1)
#pragma unroll
        for (int mi = 0; mi < 2; mi++)
#pragma unroll
            for (int i = 0; i < 4; i++)
                psum[mi][i] += __shfl_xor(psum[mi][i], o, 64);

    short* aob = opart + (size_t)hf * 4096 * 1024 + ((size_t)(b * 2048 + qw) * 1024) + h * 64;
#pragma unroll
    for (int mi = 0; mi < 2; mi++)
#pragma unroll
        for (int ct = 0; ct < 4; ct++)
#pragma unroll
            for (int i = 0; i < 4; i++) {
                int q = mi * 16 + lg * 4 + i;
                aob[(size_t)q * 1024 + ct * 16 + lr] = f2bf(oacc[mi][ct][i]);
            }
    if (lr == 0) {
#pragma unroll
        for (int mi = 0; mi < 2; mi++)
#pragma unroll
            for (int i = 0; i < 4; i++)
                lsump[hf * 65536 + bh * 2048 + qw + mi * 16 + lg * 4 + i] = psum[mi][i];
    }
}

// ---------- combine split-K partials: ao = (O0+O1)/(l0+l1), bf16 ----------
__global__ void k_comb(const short* __restrict__ op, const float* __restrict__ ls,
                       short* __restrict__ ao) {
    int i = (blockIdx.x * 256 + threadIdx.x) * 4;     // over 4096*1024
    int row = i >> 10, col = i & 1023;
    int idx = ((row >> 11) * 16 + (col >> 6)) * 2048 + (row & 2047);
    float rl = 1.0f / (ls[idx] + ls[65536 + idx]);
    short4 a = *(const short4*)(op + i);
    short4 c = *(const short4*)(op + 4194304 + i);
    short4 o;
    o.x = f2bf((bf2f(a.x) + bf2f(c.x)) * rl);
    o.y = f2bf((bf2f(a.y) + bf2f(c.y)) * rl);
    o.z = f2bf((bf2f(a.z) + bf2f(c.z)) * rl);
    o.w = f2bf((bf2f(a.w) + bf2f(c.w)) * rl);
    *(short4*)(ao + i) = o;
}

// ---------- residual + double cosine_norm (base/outf may alias: no restrict on them) ----------
__global__ void k_resnorm(const float* base, const float* __restrict__ pre,
                          const float* __restrict__ alpha, float* outf,
                          short* __restrict__ outb) {
    __shared__ float red1[4], red2[4];
    int row = blockIdx.x;
    int t = threadIdx.x;
    int w = t >> 6;
    const float4 p = *(const float4*)(pre + (size_t)row * 1024 + t * 4);
    float ss = p.x * p.x + p.y * p.y + p.z * p.z + p.w * p.w;
#pragma unroll
    for (int o = 1; o < 64; o <<= 1) ss += __shfl_xor(ss, o, 64);
    if ((t & 63) == 0) red1[w] = ss;
    __syncthreads();
    float inv1 = 1.0f / fmaxf(sqrtf(red1[0] + red1[1] + red1[2] + red1[3]), 1e-6f);
    const float4 bx = *(const float4*)(base + (size_t)row * 1024 + t * 4);
    const float4 av = *(const float4*)(alpha + t * 4);
    float4 tm;
    tm.x = bx.x + av.x * (p.x * inv1 - bx.x);
    tm.y = bx.y + av.y * (p.y * inv1 - bx.y);
    tm.z = bx.z + av.z * (p.z * inv1 - bx.z);
    tm.w = bx.w + av.w * (p.w * inv1 - bx.w);
    float ss2 = tm.x * tm.x + tm.y * tm.y + tm.z * tm.z + tm.w * tm.w;
#pragma unroll
    for (int o = 1; o < 64; o <<= 1) ss2 += __shfl_xor(ss2, o, 64);
    if ((t & 63) == 0) red2[w] = ss2;
    __syncthreads();
    float inv2 = 1.0f / fmaxf(sqrtf(red2[0] + red2[1] + red2[2] + red2[3]), 1e-6f);
    float4 hv;
    hv.x = tm.x * inv2; hv.y = tm.y * inv2; hv.z = tm.z * inv2; hv.w = tm.w * inv2;
    if (outf) *(float4*)(outf + (size_t)row * 1024 + t * 4) = hv;
    if (outb) {
        short4 o4;
        o4.x = f2bf(hv.x); o4.y = f2bf(hv.y); o4.z = f2bf(hv.z); o4.w = f2bf(hv.w);
        *(short4*)(outb + (size_t)row * 1024 + t * 4) = o4;
    }
}

// ---------- launch ----------
// Workspace (lifetime-overlaid, peak 76,152,832 B = known-safe):
//  [0, 25821184)   weights bf16^T (wqkvT, woT, wugT interleaved, wdownT) + rope tables
//  B 25821184      xbf(#1-#4) -> vt(#6-#7) -> h1bf(#10-#11)              8 MB
//  C 34209792      qkvb(#4-#6) 24MB -> opart[2](#7-#8) 16MB -> hA(#9-#10) 16MB -> wmlp(#11-#12) 22.5MB
//  50987008        lsum (#7-#8) 0.5MB
//  52035584        ao (#8-#9) 8MB
//  59375616        qn(#5-#7) -> hM(#12-#13) 16MB
//  67764224        kn(#5-#7)
// NOTE: k_gemm256<2> reads B rows 5504..5631 (pad tail) -> spills 256KB into wdownT
// region (garbage, in-bounds of ws); results for those cols are store-guarded away.
extern "C" void kernel_launch(void* const* d_in, const int* in_sizes, int n_in,
                              void* d_out, int out_size, void* d_ws, size_t ws_size,
                              hipStream_t stream) {
    (void)in_sizes; (void)n_in; (void)out_size; (void)ws_size;
    const float* x   = (const float*)d_in[0];
    const float* Wq  = (const float*)d_in[1];
    const float* Wk  = (const float*)d_in[2];
    const float* Wv  = (const float*)d_in[3];
    const float* Wo  = (const float*)d_in[4];
    const float* sqk = (const float*)d_in[5];
    const float* aA  = (const float*)d_in[6];
    const float* Wup = (const float*)d_in[7];
    const float* Wg  = (const float*)d_in[8];
    const float* Wd  = (const float*)d_in[9];
    const float* su  = (const float*)d_in[10];
    const float* sv  = (const float*)d_in[11];
    const float* aM  = (const float*)d_in[12];

    char* ws = (char*)d_ws;
    short* wqkvT  = (short*)(ws + 0);          // [3072][1024]
    short* woT    = (short*)(ws + 6291456);    // [1024][1024]
    short* wugT   = (short*)(ws + 8388608);    // [5504][1024] interleaved up/gate
    short* wdownT = (short*)(ws + 19660800);   // [1024][2752]
    float* cost   = (float*)(ws + 25296896);
    float* sint   = (float*)(ws + 25559040);
    short* xbf    = (short*)(ws + 25821184);
    short* qkvb   = (short*)(ws + 34209792);   // [4096][3072] bf16
    short* qn     = (short*)(ws + 59375616);
    short* kn     = (short*)(ws + 67764224);
    short* vt     = (short*)(ws + 25821184);   // reuse xbf
    short* opart  = (short*)(ws + 34209792);   // reuse qkvb: [2][4096][1024] bf16
    float* lsum   = (float*)(ws + 50987008);   // [2][32][2048] f32
    short* ao     = (short*)(ws + 52035584);   // [4096][1024] bf16
    float* hA     = (float*)(ws + 34209792);   // reuse opart after comb
    float* h1f    = (float*)d_out;             // d_out doubles as h1 storage
    short* h1bf   = (short*)(ws + 25821184);   // reuse vt
    short* wmlp   = (short*)(ws + 34209792);   // reuse hA: [4096][2752]
    float* hM     = (float*)(ws + 59375616);   // reuse qn/kn

    k_cvt_bf16<<<4096, 256, 0, stream>>>(x, xbf, 4194304);
    k_transpose_cvt<<<dim3(32, 32), 256, 0, stream>>>(Wq, wqkvT,           1024, 1024, 1024, 1024, 1, 0);
    k_transpose_cvt<<<dim3(32, 32), 256, 0, stream>>>(Wk, wqkvT + 1048576, 1024, 1024, 1024, 1024, 1, 0);
    k_transpose_cvt<<<dim3(32, 32), 256, 0, stream>>>(Wv, wqkvT + 2097152, 1024, 1024, 1024, 1024, 1, 0);
    k_transpose_cvt<<<dim3(32, 32), 256, 0, stream>>>(Wo, woT,             1024, 1024, 1024, 1024, 1, 0);
    k_transpose_cvt<<<dim3(86, 32), 256, 0, stream>>>(Wup, wugT, 1024, 2730, 1024, 2752, 2, 0);
    k_transpose_cvt<<<dim3(86, 32), 256, 0, stream>>>(Wg,  wugT, 1024, 2730, 1024, 2752, 2, 1);
    k_transpose_cvt<<<dim3(32, 86), 256, 0, stream>>>(Wd,  wdownT, 2730, 1024, 2752, 1024, 1, 0);
    k_freqs<<<256, 256, 0, stream>>>(cost, sint);

    k_gemm256<1><<<192, 512, 0, stream>>>(xbf, wqkvT, qkvb, 4096, 1024, 3072, nullptr, nullptr);
    k_rope<<<16384, 256, 0, stream>>>(qkvb, cost, sint, sqk, qn, kn);
    k_vtrans<<<1024, 256, 0, stream>>>(qkvb, vt);
    k_attn<<<512, 512, 0, stream>>>(qn, kn, vt, opart, lsum);
    k_comb<<<4096, 256, 0, stream>>>(opart, lsum, ao);
    k_gemm128<0><<<dim3(32, 8), 256, 0, stream>>>(ao, woT, hA, 4096, 1024, 1024);
    k_resnorm<<<4096, 256, 0, stream>>>(x, hA, aA, h1f, h1bf);
    k_gemm256<2><<<352, 512, 0, stream>>>(h1bf, wugT, wmlp, 4096, 1024, 2752, su, sv);
    k_gemm128<0><<<dim3(32, 8), 256, 0, stream>>>(wmlp, wdownT, hM, 4096, 1024, 2752);
    k_resnorm<<<4096, 256, 0, stream>>>(h1f, hM, aM, (float*)d_out, (short*)nullptr);
}

// Round 9
// 351.096 us; speedup vs baseline: 1.1173x; 1.1173x over previous
//
#include <hip/hip_runtime.h>
#include <math.h>

#define DEVI __device__ __forceinline__

typedef __attribute__((ext_vector_type(4))) float f32x4;
typedef __attribute__((ext_vector_type(8))) short bf16x8;

// ---------- helpers ----------
DEVI short f2bf(float f) {                    // f32 -> bf16 (RNE)
    union { float f; unsigned u; } v; v.f = f;
    unsigned r = v.u + 0x7fffu + ((v.u >> 16) & 1u);
    return (short)(r >> 16);
}
DEVI float bf2f(short s) {
    union { unsigned u; float f; } v; v.u = ((unsigned)(unsigned short)s) << 16;
    return v.f;
}

DEVI f32x4 mfma16(bf16x8 a, bf16x8 b, f32x4 c) {
    return __builtin_amdgcn_mfma_f32_16x16x32_bf16(a, b, c, 0, 0, 0);
}

DEVI void gload16(const short* g, short* l) {  // async global->LDS, 16B/lane
    __builtin_amdgcn_global_load_lds((__attribute__((address_space(1))) void*)(g),
                                     (__attribute__((address_space(3))) void*)(l),
                                     16, 0, 0);
}

// ---------- elementwise f32 -> bf16 ----------
__global__ void k_cvt_bf16(const float* __restrict__ in, short* __restrict__ out, int n) {
    int i = (blockIdx.x * blockDim.x + threadIdx.x) * 4;
    if (i >= n) return;
    float4 v = *(const float4*)(in + i);
    short4 o;
    o.x = f2bf(v.x); o.y = f2bf(v.y); o.z = f2bf(v.z); o.w = f2bf(v.w);
    *(short4*)(out + i) = o;
}

// ---------- transpose + convert: in f32 [R][C] -> out bf16 rows (c*rmul+radd), zero pad ----------
__global__ void k_transpose_cvt(const float* __restrict__ in, short* __restrict__ out,
                                int R, int C, int Rpad, int Cpad, int rmul, int radd) {
    __shared__ float tile[32][33];
    int c0 = blockIdx.x * 32;   // C-dim (out rows)
    int r0 = blockIdx.y * 32;   // R-dim (out cols)
    int tx = threadIdx.x & 31, ty = threadIdx.x >> 5;   // ty in [0,8)
#pragma unroll
    for (int i = 0; i < 4; i++) {
        int r = r0 + ty + 8 * i, c = c0 + tx;
        tile[ty + 8 * i][tx] = (r < R && c < C) ? in[(size_t)r * C + c] : 0.0f;
    }
    __syncthreads();
#pragma unroll
    for (int i = 0; i < 4; i++) {
        int oc = c0 + ty + 8 * i;   // out row (pre-interleave)
        int orr = r0 + tx;          // out col
        if (oc < Cpad && orr < Rpad)
            out[(size_t)(oc * rmul + radd) * Rpad + orr] = f2bf(tile[tx][ty + 8 * i]);
    }
}

// ---------- RoPE freq tables (f64 for reference fidelity) ----------
__global__ void k_freqs(float* __restrict__ cost, float* __restrict__ sint) {
    int i = blockIdx.x * blockDim.x + threadIdx.x;   // [0, 2048*32)
    int s = i >> 5, j = i & 31;
    double inv = pow(10000.0, -(double)j / 32.0);
    double f = (double)s * inv;
    cost[i] = (float)cos(f);
    sint[i] = (float)sin(f);
}

// ---------- GEMM 128x128x32, double-buffered LDS, XCD-chunked 1D grid ----------
// EPI: 0 = f32 out (stride N), 1 = bf16 out (stride N),
//      2 = SwiGLU-interleaved: B rows alternate up/gate, j = col/2,
//          w = (u*s_u[j]) * silu(g*s_v[j]*32), bf16 out stride N/2.
// Grid must be 1D with gridDim.x % 8 == 0 (bijective XCD remap).
template <int EPI>
__launch_bounds__(256)
__global__ void k_gemm128(const short* __restrict__ A, const short* __restrict__ BT,
                          void* __restrict__ Cv, int M, int N, int K,
                          const float* __restrict__ s_u, const float* __restrict__ s_v) {
    __shared__ __align__(16) short As[2 * 128 * 32];
    __shared__ __align__(16) short Bs[2 * 128 * 32];
    const int t = threadIdx.x;
    const int w = t >> 6;
    const int lane = t & 63;
    const int lr = lane & 15, lg = lane >> 4;
    const int nwg = (int)gridDim.x;
    const int wg = ((int)blockIdx.x & 7) * (nwg >> 3) + ((int)blockIdx.x >> 3);
    const int MT = M >> 7;
    const int m0 = (wg % MT) << 7;
    const int n0 = (wg / MT) << 7;
    const int wr = (w >> 1) * 64, wc = (w & 1) * 64;

    // strength-reduced staging pointers: thread t loads rows (t>>2) and (t>>2)+64,
    // col-group (t&3)*8; advance by 32 shorts per K-step.
    const int srow = t >> 2, scol = (t & 3) << 3;
    const short* Ap0 = A + (size_t)(m0 + srow) * K + scol;
    const short* Ap1 = A + (size_t)(m0 + srow + 64) * K + scol;
    const short* Bp0 = BT + (size_t)(n0 + srow) * K + scol;
    const short* Bp1 = BT + (size_t)(n0 + srow + 64) * K + scol;
    const int d0 = (w * 64) * 8;          // wave-uniform LDS dest (+ lane*8 in HW)
    const int d1 = (w * 64 + 256) * 8;

    f32x4 acc[4][4];
#pragma unroll
    for (int m = 0; m < 4; m++)
#pragma unroll
        for (int n = 0; n < 4; n++)
            acc[m][n] = (f32x4){0.f, 0.f, 0.f, 0.f};

    const int nk = K >> 5;
    // prologue: stage tile 0 into buffer 0
    gload16(Ap0, As + d0); gload16(Ap1, As + d1);
    gload16(Bp0, Bs + d0); gload16(Bp1, Bs + d1);
    Ap0 += 32; Ap1 += 32; Bp0 += 32; Bp1 += 32;

    for (int kt = 0; kt < nk; kt++) {
        __syncthreads();                  // vmcnt(0) drain -> buf[kt&1] resident
        if (kt + 1 < nk) {                // prefetch t+1 into other buffer
            const int bo = ((kt + 1) & 1) * 4096;
            gload16(Ap0, As + bo + d0); gload16(Ap1, As + bo + d1);
            gload16(Bp0, Bs + bo + d0); gload16(Bp1, Bs + bo + d1);
            Ap0 += 32; Ap1 += 32; Bp0 += 32; Bp1 += 32;
        }
        const short* asb = As + (kt & 1) * 4096;
        const short* bsb = Bs + (kt & 1) * 4096;
        bf16x8 af[4], bfr[4];
#pragma unroll
        for (int m = 0; m < 4; m++)
            af[m] = *(const bf16x8*)&asb[(wr + m * 16 + lr) * 32 + lg * 8];
#pragma unroll
        for (int n = 0; n < 4; n++)
            bfr[n] = *(const bf16x8*)&bsb[(wc + n * 16 + lr) * 32 + lg * 8];
#pragma unroll
        for (int m = 0; m < 4; m++)
#pragma unroll
            for (int n = 0; n < 4; n++)
                acc[m][n] = mfma16(af[m], bfr[n], acc[m][n]);
    }

#pragma unroll
    for (int m = 0; m < 4; m++)
#pragma unroll
        for (int n = 0; n < 4; n++) {
            int row = m0 + wr + m * 16 + lg * 4;
            int col = n0 + wc + n * 16 + lr;
            if (EPI == 2) {
                int j = col >> 1;
                int jc = j < 2730 ? j : 2729;
                float su = s_u[jc];
                float sg = s_v[jc] * 32.0f;
#pragma unroll
                for (int i = 0; i < 4; i++) {
                    float own = acc[m][n][i];
                    float oth = __shfl_xor(own, 1, 64);
                    float u = (lr & 1) ? oth : own;
                    float g = (lr & 1) ? own : oth;
                    float uu = u * su;
                    float vv = g * sg;
                    float wv = uu * vv / (1.0f + expf(-vv));
                    if (!(lr & 1))
                        ((short*)Cv)[(size_t)(row + i) * (N >> 1) + j] = f2bf(wv);
                }
            } else {
#pragma unroll
                for (int i = 0; i < 4; i++) {
                    if (EPI == 1)
                        ((short*)Cv)[(size_t)(row + i) * N + col] = f2bf(acc[m][n][i]);
                    else
                        ((float*)Cv)[(size_t)(row + i) * N + col] = acc[m][n][i];
                }
            }
        }
}

// ---------- RoPE + cosine_norm for q,k. qkvb bf16 [4096][3072] -> qn,kn bf16 [B][H][S][64] ----------
__global__ void k_rope(const short* __restrict__ qkvb, const float* __restrict__ cost,
                       const float* __restrict__ sint, const float* __restrict__ sqk,
                       short* __restrict__ qn, short* __restrict__ kn) {
    int wid = blockIdx.x * 4 + (threadIdx.x >> 6);   // [0, 65536)
    int lane = threadIdx.x & 63;
    int h = wid & 15;
    int s = (wid >> 4) & 2047;
    int b = wid >> 15;
    int row = b * 2048 + s;
    int j = lane & 31;
    float cs = cost[s * 32 + j];
    float sn = sint[s * 32 + j];
    float eff = sqk[h * 64 + lane] * 32.0f;          // s_qk * sqrt(DIM)
    size_t inbase = (size_t)row * 3072 + h * 64 + lane;
    size_t outbase = ((size_t)(b * 16 + h) * 2048 + s) * 64 + lane;
    {   // q  (extra *8 = sqrt(HD) logit scale folded in)
        float v = bf2f(qkvb[inbase]);
        float vp = __shfl_xor(v, 32, 64);
        float vr = (lane < 32) ? v * cs - vp * sn : v * cs + vp * sn;
        float ss = vr * vr;
#pragma unroll
        for (int o = 1; o < 64; o <<= 1) ss += __shfl_xor(ss, o, 64);
        float sc = eff * 8.0f / fmaxf(sqrtf(ss), 1e-6f);
        qn[outbase] = f2bf(vr * sc);
    }
    {   // k
        float v = bf2f(qkvb[inbase + 1024]);
        float vp = __shfl_xor(v, 32, 64);
        float vr = (lane < 32) ? v * cs - vp * sn : v * cs + vp * sn;
        float ss = vr * vr;
#pragma unroll
        for (int o = 1; o < 64; o <<= 1) ss += __shfl_xor(ss, o, 64);
        float sc = eff / fmaxf(sqrtf(ss), 1e-6f);
        kn[outbase] = f2bf(vr * sc);
    }
}

// ---------- V transpose: qkvb v-part bf16 -> vt bf16 [B][H][64][2048] ----------
__global__ void k_vtrans(const short* __restrict__ qkvb, short* __restrict__ vt) {
    __shared__ short tile[64][72];
    int blk = blockIdx.x;
    int st = blk & 31, h = (blk >> 5) & 15, b = blk >> 9;
    int s0 = st * 64;
    int t = threadIdx.x;
    int sl = t >> 2, c0 = (t & 3) * 16;
    const short* src = qkvb + (size_t)(b * 2048 + s0 + sl) * 3072 + 2048 + h * 64 + c0;
    bf16x8 a0 = *(const bf16x8*)src;
    bf16x8 a1 = *(const bf16x8*)(src + 8);
#pragma unroll
    for (int jj = 0; jj < 8; jj++) { tile[sl][c0 + jj] = a0[jj]; tile[sl][c0 + 8 + jj] = a1[jj]; }
    __syncthreads();
    int hd = t >> 2, sc = (t & 3) * 16;
    bf16x8 p0, p1;
#pragma unroll
    for (int jj = 0; jj < 8; jj++) { p0[jj] = tile[sc + jj][hd]; p1[jj] = tile[sc + 8 + jj][hd]; }
    size_t obase = ((size_t)((b * 16 + h) * 64 + hd)) * 2048 + s0 + sc;
    *(bf16x8*)&vt[obase] = p0;
    *(bf16x8*)&vt[obase + 8] = p1;
}

// ---------- flash attention (causal), static-max softmax, split-K x2, XCD-binned ----------
__launch_bounds__(512)
__global__ void k_attn(const short* __restrict__ qn, const short* __restrict__ kn,
                       const short* __restrict__ vt, short* __restrict__ opart,
                       float* __restrict__ lsump) {
    __shared__ __align__(16) short Ks[2][64 * 64];   // 2 x 8 KB
    __shared__ __align__(16) short Vs[2][64 * 64];   // 2 x 8 KB
    __shared__ __align__(16) short Ps[8][32 * 64];   // 8 x 4 KB
    const int t = threadIdx.x;
    const int w = t >> 6, lane = t & 63;
    const int bid = blockIdx.x;
    const int xcd = bid & 7, kk_ = bid >> 3;
    const int bhg = xcd + ((kk_ >> 4) << 3);         // 0..31
    const int xi = kk_ & 15;
    const int qb = 7 - (xi >> 1), hf = xi & 1;
    const int h = bhg & 15, b = bhg >> 4;
    const int bh = b * 16 + h;
    const int qw = qb * 256 + w * 32;
    const int lr = lane & 15, lg = lane >> 4;
    const short* Qb = qn + (size_t)bh * 2048 * 64;
    const short* Kb = kn + (size_t)bh * 2048 * 64;
    const short* Vb = vt + (size_t)bh * 64 * 2048;
    char* pwc = (char*)&Ps[w][0];

    bf16x8 qf[2][2];
#pragma unroll
    for (int mi = 0; mi < 2; mi++)
#pragma unroll
        for (int kk = 0; kk < 2; kk++)
            qf[mi][kk] = *(const bf16x8*)&Qb[(size_t)(qw + mi * 16 + lr) * 64 + kk * 32 + lg * 8];

    f32x4 oacc[2][4];
#pragma unroll
    for (int mi = 0; mi < 2; mi++)
#pragma unroll
        for (int ct = 0; ct < 4; ct++) oacc[mi][ct] = (f32x4){0.f, 0.f, 0.f, 0.f};
    float psum[2][4];
#pragma unroll
    for (int mi = 0; mi < 2; mi++)
#pragma unroll
        for (int i = 0; i < 4; i++) psum[mi][i] = 0.0f;

    const int ktn = 2 * qb + 2;
    const int kt0 = hf * ktn, kt1 = kt0 + ktn;

#define STAGE_KV(bi, kbase)                                                          \
    {                                                                                \
        int row = w * 8 + (lane >> 3);                                               \
        int scol = (lane & 7) ^ (row & 7);                                           \
        gload16(Kb + (size_t)((kbase) + row) * 64 + scol * 8,                        \
                &Ks[bi][(w * 8) * 64]);                                              \
        gload16(Vb + (size_t)row * 2048 + (kbase) + scol * 8,                        \
                &Vs[bi][(w * 8) * 64]);                                              \
    }

    STAGE_KV(0, kt0 << 6);

    for (int kt = kt0; kt < kt1; kt++) {
        const int kbase = kt << 6;
        const int cur = (kt - kt0) & 1;
        __syncthreads();                      // drains vmcnt -> buf cur resident
        if (kt + 1 < kt1) STAGE_KV(cur ^ 1, (kt + 1) << 6);

        bf16x8 kf[4][2];
#pragma unroll
        for (int ni = 0; ni < 4; ni++)
#pragma unroll
            for (int kk = 0; kk < 2; kk++) {
                int row = ni * 16 + lr;
                kf[ni][kk] = *(const bf16x8*)&Ks[cur][row * 64 + (((kk * 4 + lg) ^ (row & 7)) << 3)];
            }
        f32x4 sv[2][4];
#pragma unroll
        for (int mi = 0; mi < 2; mi++)
#pragma unroll
            for (int ni = 0; ni < 4; ni++) {
                f32x4 s = (f32x4){0.f, 0.f, 0.f, 0.f};
                s = mfma16(qf[mi][0], kf[ni][0], s);
                s = mfma16(qf[mi][1], kf[ni][1], s);
                sv[mi][ni] = s;
            }
        if (kbase + 63 > qw) {
#pragma unroll
            for (int mi = 0; mi < 2; mi++)
#pragma unroll
                for (int ni = 0; ni < 4; ni++)
#pragma unroll
                    for (int i = 0; i < 4; i++) {
                        int qg = qw + mi * 16 + lg * 4 + i;
                        int kg = kbase + ni * 16 + lr;
                        if (kg > qg) sv[mi][ni][i] = -3.0e38f;
                    }
        }
#pragma unroll
        for (int mi = 0; mi < 2; mi++) {
#pragma unroll
            for (int ni = 0; ni < 4; ni++)
#pragma unroll
                for (int i = 0; i < 4; i++) {
                    float p = exp2f((sv[mi][ni][i] - 9.0f) * 1.44269504f);
                    sv[mi][ni][i] = p;
                    psum[mi][i] += p;
                }
#pragma unroll
            for (int ni = 0; ni < 4; ni++)
#pragma unroll
                for (int i = 0; i < 4; i++) {
                    int row = mi * 16 + lg * 4 + i;
                    int col = ni * 16 + lr;
                    unsigned off = (unsigned)(row * 128 + col * 2) ^ ((unsigned)(row & 7) << 4);
                    *(short*)(pwc + off) = f2bf(sv[mi][ni][i]);
                }
        }
        bf16x8 pa[2][2];
#pragma unroll
        for (int mi = 0; mi < 2; mi++)
#pragma unroll
            for (int kk = 0; kk < 2; kk++) {
                int row = mi * 16 + lr;
                unsigned off = (unsigned)(row * 128 + kk * 64 + lg * 16) ^ ((unsigned)(row & 7) << 4);
                pa[mi][kk] = *(const bf16x8*)(pwc + off);
            }
        bf16x8 vf[4][2];
#pragma unroll
        for (int ct = 0; ct < 4; ct++)
#pragma unroll
            for (int kk = 0; kk < 2; kk++) {
                int row = ct * 16 + lr;
                vf[ct][kk] = *(const bf16x8*)&Vs[cur][row * 64 + (((kk * 4 + lg) ^ (row & 7)) << 3)];
            }
#pragma unroll
        for (int mi = 0; mi < 2; mi++)
#pragma unroll
            for (int ct = 0; ct < 4; ct++) {
                oacc[mi][ct] = mfma16(pa[mi][0], vf[ct][0], oacc[mi][ct]);
                oacc[mi][ct] = mfma16(pa[mi][1], vf[ct][1], oacc[mi][ct]);
            }
    }
#undef STAGE_KV

#pragma unroll
    for (int o = 1; o < 16; o <<= 1)
#pragma unroll
        for (int mi = 0; mi < 2; mi++)
#pragma unroll
            for (int i = 0; i < 4; i++)
                psum[mi][i] += __shfl_xor(psum[mi][i], o, 64);

    short* aob = opart + (size_t)hf * 4096 * 1024 + ((size_t)(b * 2048 + qw) * 1024) + h * 64;
#pragma unroll
    for (int mi = 0; mi < 2; mi++)
#pragma unroll
        for (int ct = 0; ct < 4; ct++)
#pragma unroll
            for (int i = 0; i < 4; i++) {
                int q = mi * 16 + lg * 4 + i;
                aob[(size_t)q * 1024 + ct * 16 + lr] = f2bf(oacc[mi][ct][i]);
            }
    if (lr == 0) {
#pragma unroll
        for (int mi = 0; mi < 2; mi++)
#pragma unroll
            for (int i = 0; i < 4; i++)
                lsump[hf * 65536 + bh * 2048 + qw + mi * 16 + lg * 4 + i] = psum[mi][i];
    }
}

// ---------- combine split-K partials: ao = (O0+O1)/(l0+l1), bf16 ----------
__global__ void k_comb(const short* __restrict__ op, const float* __restrict__ ls,
                       short* __restrict__ ao) {
    int i = (blockIdx.x * 256 + threadIdx.x) * 4;     // over 4096*1024
    int row = i >> 10, col = i & 1023;
    int idx = ((row >> 11) * 16 + (col >> 6)) * 2048 + (row & 2047);
    float rl = 1.0f / (ls[idx] + ls[65536 + idx]);
    short4 a = *(const short4*)(op + i);
    short4 c = *(const short4*)(op + 4194304 + i);
    short4 o;
    o.x = f2bf((bf2f(a.x) + bf2f(c.x)) * rl);
    o.y = f2bf((bf2f(a.y) + bf2f(c.y)) * rl);
    o.z = f2bf((bf2f(a.z) + bf2f(c.z)) * rl);
    o.w = f2bf((bf2f(a.w) + bf2f(c.w)) * rl);
    *(short4*)(ao + i) = o;
}

// ---------- residual + double cosine_norm (base/outf may alias: no restrict on them) ----------
__global__ void k_resnorm(const float* base, const float* __restrict__ pre,
                          const float* __restrict__ alpha, float* outf,
                          short* __restrict__ outb) {
    __shared__ float red1[4], red2[4];
    int row = blockIdx.x;
    int t = threadIdx.x;
    int w = t >> 6;
    const float4 p = *(const float4*)(pre + (size_t)row * 1024 + t * 4);
    float ss = p.x * p.x + p.y * p.y + p.z * p.z + p.w * p.w;
#pragma unroll
    for (int o = 1; o < 64; o <<= 1) ss += __shfl_xor(ss, o, 64);
    if ((t & 63) == 0) red1[w] = ss;
    __syncthreads();
    float inv1 = 1.0f / fmaxf(sqrtf(red1[0] + red1[1] + red1[2] + red1[3]), 1e-6f);
    const float4 bx = *(const float4*)(base + (size_t)row * 1024 + t * 4);
    const float4 av = *(const float4*)(alpha + t * 4);
    float4 tm;
    tm.x = bx.x + av.x * (p.x * inv1 - bx.x);
    tm.y = bx.y + av.y * (p.y * inv1 - bx.y);
    tm.z = bx.z + av.z * (p.z * inv1 - bx.z);
    tm.w = bx.w + av.w * (p.w * inv1 - bx.w);
    float ss2 = tm.x * tm.x + tm.y * tm.y + tm.z * tm.z + tm.w * tm.w;
#pragma unroll
    for (int o = 1; o < 64; o <<= 1) ss2 += __shfl_xor(ss2, o, 64);
    if ((t & 63) == 0) red2[w] = ss2;
    __syncthreads();
    float inv2 = 1.0f / fmaxf(sqrtf(red2[0] + red2[1] + red2[2] + red2[3]), 1e-6f);
    float4 hv;
    hv.x = tm.x * inv2; hv.y = tm.y * inv2; hv.z = tm.z * inv2; hv.w = tm.w * inv2;
    if (outf) *(float4*)(outf + (size_t)row * 1024 + t * 4) = hv;
    if (outb) {
        short4 o4;
        o4.x = f2bf(hv.x); o4.y = f2bf(hv.y); o4.z = f2bf(hv.z); o4.w = f2bf(hv.w);
        *(short4*)(outb + (size_t)row * 1024 + t * 4) = o4;
    }
}

// ---------- launch ----------
// Workspace (lifetime-overlaid, peak 76,152,832 B = known-safe):
//  [0, 25821184)   weights bf16^T (wqkvT, woT, wugT interleaved, wdownT) + rope tables
//  B 25821184      xbf(#1-#4) -> vt(#6-#7) -> h1bf(#10-#11)              8 MB
//  C 34209792      qkvb(#4-#6) 24MB -> opart[2](#7-#8) 16MB -> hA(#9-#10) 16MB -> wmlp(#11-#12) 22.5MB
//  50987008        lsum (#7-#8) 0.5MB
//  52035584        ao (#8-#9) 8MB
//  59375616        qn(#5-#7) -> hM(#12-#13) 16MB
//  67764224        kn(#5-#7)
extern "C" void kernel_launch(void* const* d_in, const int* in_sizes, int n_in,
                              void* d_out, int out_size, void* d_ws, size_t ws_size,
                              hipStream_t stream) {
    (void)in_sizes; (void)n_in; (void)out_size; (void)ws_size;
    const float* x   = (const float*)d_in[0];
    const float* Wq  = (const float*)d_in[1];
    const float* Wk  = (const float*)d_in[2];
    const float* Wv  = (const float*)d_in[3];
    const float* Wo  = (const float*)d_in[4];
    const float* sqk = (const float*)d_in[5];
    const float* aA  = (const float*)d_in[6];
    const float* Wup = (const float*)d_in[7];
    const float* Wg  = (const float*)d_in[8];
    const float* Wd  = (const float*)d_in[9];
    const float* su  = (const float*)d_in[10];
    const float* sv  = (const float*)d_in[11];
    const float* aM  = (const float*)d_in[12];

    char* ws = (char*)d_ws;
    short* wqkvT  = (short*)(ws + 0);          // [3072][1024]
    short* woT    = (short*)(ws + 6291456);    // [1024][1024]
    short* wugT   = (short*)(ws + 8388608);    // [5504][1024] interleaved up/gate
    short* wdownT = (short*)(ws + 19660800);   // [1024][2752]
    float* cost   = (float*)(ws + 25296896);
    float* sint   = (float*)(ws + 25559040);
    short* xbf    = (short*)(ws + 25821184);
    short* qkvb   = (short*)(ws + 34209792);   // [4096][3072] bf16
    short* qn     = (short*)(ws + 59375616);
    short* kn     = (short*)(ws + 67764224);
    short* vt     = (short*)(ws + 25821184);   // reuse xbf
    short* opart  = (short*)(ws + 34209792);   // reuse qkvb: [2][4096][1024] bf16
    float* lsum   = (float*)(ws + 50987008);   // [2][32][2048] f32
    short* ao     = (short*)(ws + 52035584);   // [4096][1024] bf16
    float* hA     = (float*)(ws + 34209792);   // reuse opart after comb
    float* h1f    = (float*)d_out;             // d_out doubles as h1 storage
    short* h1bf   = (short*)(ws + 25821184);   // reuse vt
    short* wmlp   = (short*)(ws + 34209792);   // reuse hA: [4096][2752]
    float* hM     = (float*)(ws + 59375616);   // reuse qn/kn

    k_cvt_bf16<<<4096, 256, 0, stream>>>(x, xbf, 4194304);
    k_transpose_cvt<<<dim3(32, 32), 256, 0, stream>>>(Wq, wqkvT,           1024, 1024, 1024, 1024, 1, 0);
    k_transpose_cvt<<<dim3(32, 32), 256, 0, stream>>>(Wk, wqkvT + 1048576, 1024, 1024, 1024, 1024, 1, 0);
    k_transpose_cvt<<<dim3(32, 32), 256, 0, stream>>>(Wv, wqkvT + 2097152, 1024, 1024, 1024, 1024, 1, 0);
    k_transpose_cvt<<<dim3(32, 32), 256, 0, stream>>>(Wo, woT,             1024, 1024, 1024, 1024, 1, 0);
    k_transpose_cvt<<<dim3(86, 32), 256, 0, stream>>>(Wup, wugT, 1024, 2730, 1024, 2752, 2, 0);
    k_transpose_cvt<<<dim3(86, 32), 256, 0, stream>>>(Wg,  wugT, 1024, 2730, 1024, 2752, 2, 1);
    k_transpose_cvt<<<dim3(32, 86), 256, 0, stream>>>(Wd,  wdownT, 2730, 1024, 2752, 1024, 1, 0);
    k_freqs<<<256, 256, 0, stream>>>(cost, sint);

    k_gemm128<1><<<768, 256, 0, stream>>>(xbf, wqkvT, qkvb, 4096, 3072, 1024, nullptr, nullptr);
    k_rope<<<16384, 256, 0, stream>>>(qkvb, cost, sint, sqk, qn, kn);
    k_vtrans<<<1024, 256, 0, stream>>>(qkvb, vt);
    k_attn<<<512, 512, 0, stream>>>(qn, kn, vt, opart, lsum);
    k_comb<<<4096, 256, 0, stream>>>(opart, lsum, ao);
    k_gemm128<0><<<256, 256, 0, stream>>>(ao, woT, hA, 4096, 1024, 1024, nullptr, nullptr);
    k_resnorm<<<4096, 256, 0, stream>>>(x, hA, aA, h1f, h1bf);
    k_gemm128<2><<<1376, 256, 0, stream>>>(h1bf, wugT, wmlp, 4096, 5504, 1024, su, sv);
    k_gemm128<0><<<256, 256, 0, stream>>>(wmlp, wdownT, hM, 4096, 1024, 2752, nullptr, nullptr);
    k_resnorm<<<4096, 256, 0, stream>>>(h1f, hM, aM, (float*)d_out, (short*)nullptr);
}

// Round 10
// 332.287 us; speedup vs baseline: 1.1805x; 1.0566x over previous
//
#include <hip/hip_runtime.h>
#include <math.h>

#define DEVI __device__ __forceinline__

typedef __attribute__((ext_vector_type(4))) float f32x4;
typedef __attribute__((ext_vector_type(8))) short bf16x8;

// ---------- helpers ----------
DEVI short f2bf(float f) {                    // f32 -> bf16 (RNE)
    union { float f; unsigned u; } v; v.f = f;
    unsigned r = v.u + 0x7fffu + ((v.u >> 16) & 1u);
    return (short)(r >> 16);
}
DEVI float bf2f(short s) {
    union { unsigned u; float f; } v; v.u = ((unsigned)(unsigned short)s) << 16;
    return v.f;
}

DEVI f32x4 mfma16(bf16x8 a, bf16x8 b, f32x4 c) {
    return __builtin_amdgcn_mfma_f32_16x16x32_bf16(a, b, c, 0, 0, 0);
}

DEVI void gload16(const short* g, short* l) {  // async global->LDS, 16B/lane
    __builtin_amdgcn_global_load_lds((__attribute__((address_space(1))) void*)(g),
                                     (__attribute__((address_space(3))) void*)(l),
                                     16, 0, 0);
}

// ---------- elementwise f32 -> bf16 ----------
__global__ void k_cvt_bf16(const float* __restrict__ in, short* __restrict__ out, int n) {
    int i = (blockIdx.x * blockDim.x + threadIdx.x) * 4;
    if (i >= n) return;
    float4 v = *(const float4*)(in + i);
    short4 o;
    o.x = f2bf(v.x); o.y = f2bf(v.y); o.z = f2bf(v.z); o.w = f2bf(v.w);
    *(short4*)(out + i) = o;
}

// ---------- transpose + convert: in f32 [R][C] -> out bf16 rows (c*rmul+radd), zero pad ----------
__global__ void k_transpose_cvt(const float* __restrict__ in, short* __restrict__ out,
                                int R, int C, int Rpad, int Cpad, int rmul, int radd) {
    __shared__ float tile[32][33];
    int c0 = blockIdx.x * 32;
    int r0 = blockIdx.y * 32;
    int tx = threadIdx.x & 31, ty = threadIdx.x >> 5;
#pragma unroll
    for (int i = 0; i < 4; i++) {
        int r = r0 + ty + 8 * i, c = c0 + tx;
        tile[ty + 8 * i][tx] = (r < R && c < C) ? in[(size_t)r * C + c] : 0.0f;
    }
    __syncthreads();
#pragma unroll
    for (int i = 0; i < 4; i++) {
        int oc = c0 + ty + 8 * i;
        int orr = r0 + tx;
        if (oc < Cpad && orr < Rpad)
            out[(size_t)(oc * rmul + radd) * Rpad + orr] = f2bf(tile[tx][ty + 8 * i]);
    }
}

// ---------- RoPE freq tables (f64 for reference fidelity) ----------
__global__ void k_freqs(float* __restrict__ cost, float* __restrict__ sint) {
    int i = blockIdx.x * blockDim.x + threadIdx.x;   // [0, 2048*32)
    int s = i >> 5, j = i & 31;
    double inv = pow(10000.0, -(double)j / 32.0);
    double f = (double)s * inv;
    cost[i] = (float)cos(f);
    sint[i] = (float)sin(f);
}

// ---------- GEMM 128x128x32, double-buffered LDS, XCD-chunked 1D grid, optional split-K ----------
// EPI: 0 = f32 out, 1 = bf16 out, 2 = SwiGLU-interleaved (B rows alternate up/gate),
//      3 = fused QKV epilogue: rope + cosine-norm + s_qk for q/k cols, plain bf16 for v.
// nsplit: 1 or 2. For 2, blocks split into K-halves; half 1 writes Cv1.
// Grid 1D, gridDim.x % 8 == 0.
template <int EPI>
__launch_bounds__(256)
__global__ void k_gemm128(const short* __restrict__ A, const short* __restrict__ BT,
                          void* __restrict__ Cv, void* __restrict__ Cv1,
                          int M, int N, int K, int nkblk, int nsplit,
                          const float* __restrict__ s_u, const float* __restrict__ s_v,
                          const float* __restrict__ cost, const float* __restrict__ sint,
                          const float* __restrict__ sqk,
                          short* __restrict__ qn, short* __restrict__ kn,
                          short* __restrict__ vraw) {
    __shared__ __align__(16) short As[2 * 128 * 32];
    __shared__ __align__(16) short Bs[2 * 128 * 32];
    const int t = threadIdx.x;
    const int w = t >> 6;
    const int lane = t & 63;
    const int lr = lane & 15, lg = lane >> 4;
    const int nwg = (int)gridDim.x;
    int wg = ((int)blockIdx.x & 7) * (nwg >> 3) + ((int)blockIdx.x >> 3);
    int half = 0;
    if (nsplit == 2) {
        const int per = nwg >> 1;
        half = wg >= per;
        wg -= half * per;
    }
    const int MT = M >> 7;
    const int m0 = (wg % MT) << 7;
    const int n0 = (wg / MT) << 7;
    const int koff = half * nkblk * 32;
    const int wr = (w >> 1) * 64, wc = (w & 1) * 64;

    const int srow = t >> 2, scol = (t & 3) << 3;
    const short* Ap0 = A + (size_t)(m0 + srow) * K + koff + scol;
    const short* Ap1 = A + (size_t)(m0 + srow + 64) * K + koff + scol;
    const short* Bp0 = BT + (size_t)(n0 + srow) * K + koff + scol;
    const short* Bp1 = BT + (size_t)(n0 + srow + 64) * K + koff + scol;
    const int d0 = (w * 64) * 8;
    const int d1 = (w * 64 + 256) * 8;

    f32x4 acc[4][4];
#pragma unroll
    for (int m = 0; m < 4; m++)
#pragma unroll
        for (int n = 0; n < 4; n++)
            acc[m][n] = (f32x4){0.f, 0.f, 0.f, 0.f};

    gload16(Ap0, As + d0); gload16(Ap1, As + d1);
    gload16(Bp0, Bs + d0); gload16(Bp1, Bs + d1);
    Ap0 += 32; Ap1 += 32; Bp0 += 32; Bp1 += 32;

    for (int kt = 0; kt < nkblk; kt++) {
        __syncthreads();
        if (kt + 1 < nkblk) {
            const int bo = ((kt + 1) & 1) * 4096;
            gload16(Ap0, As + bo + d0); gload16(Ap1, As + bo + d1);
            gload16(Bp0, Bs + bo + d0); gload16(Bp1, Bs + bo + d1);
            Ap0 += 32; Ap1 += 32; Bp0 += 32; Bp1 += 32;
        }
        const short* asb = As + (kt & 1) * 4096;
        const short* bsb = Bs + (kt & 1) * 4096;
        bf16x8 af[4], bfr[4];
#pragma unroll
        for (int m = 0; m < 4; m++)
            af[m] = *(const bf16x8*)&asb[(wr + m * 16 + lr) * 32 + lg * 8];
#pragma unroll
        for (int n = 0; n < 4; n++)
            bfr[n] = *(const bf16x8*)&bsb[(wc + n * 16 + lr) * 32 + lg * 8];
#pragma unroll
        for (int m = 0; m < 4; m++)
#pragma unroll
            for (int n = 0; n < 4; n++)
                acc[m][n] = mfma16(af[m], bfr[n], acc[m][n]);
    }

    if (EPI == 3) {
        // sector uniform per block: 0 = q, 1 = k, 2 = v
        const int sector = n0 >> 10;
        if (sector == 2) {
#pragma unroll
            for (int m = 0; m < 4; m++)
#pragma unroll
                for (int n = 0; n < 4; n++) {
                    int col = n0 + wc + n * 16 + lr - 2048;
                    int row = m0 + wr + m * 16 + lg * 4;
#pragma unroll
                    for (int i = 0; i < 4; i++)
                        vraw[(size_t)(row + i) * 1024 + col] = f2bf(acc[m][n][i]);
                }
        } else {
            const int h = ((n0 + wc) >> 6) & 15;
            float eff[4];
#pragma unroll
            for (int n = 0; n < 4; n++)
                eff[n] = sqk[h * 64 + n * 16 + lr] * 32.0f;   // s_qk * sqrt(DIM)
            short* dst = (sector == 0) ? qn : kn;
            const float extra = (sector == 0) ? 8.0f : 1.0f;  // sqrt(HD) folded into q
#pragma unroll
            for (int m = 0; m < 4; m++)
#pragma unroll
                for (int i = 0; i < 4; i++) {
                    int row = m0 + wr + m * 16 + lg * 4 + i;
                    int b = row >> 11, s = row & 2047;
                    float cs0 = cost[s * 32 + lr],      sn0 = sint[s * 32 + lr];
                    float cs1 = cost[s * 32 + 16 + lr], sn1 = sint[s * 32 + 16 + lr];
                    float vr0 = acc[m][0][i] * cs0 - acc[m][2][i] * sn0;
                    float vr1 = acc[m][1][i] * cs1 - acc[m][3][i] * sn1;
                    float vr2 = acc[m][2][i] * cs0 + acc[m][0][i] * sn0;
                    float vr3 = acc[m][3][i] * cs1 + acc[m][1][i] * sn1;
                    float ss = vr0 * vr0 + vr1 * vr1 + vr2 * vr2 + vr3 * vr3;
#pragma unroll
                    for (int o = 1; o < 16; o <<= 1)
                        ss += __shfl_xor(ss, o, 64);
                    float sc = extra / fmaxf(sqrtf(ss), 1e-6f);
                    size_t base = ((size_t)(b * 16 + h) * 2048 + s) * 64;
                    dst[base + lr]      = f2bf(vr0 * eff[0] * sc);
                    dst[base + 16 + lr] = f2bf(vr1 * eff[1] * sc);
                    dst[base + 32 + lr] = f2bf(vr2 * eff[2] * sc);
                    dst[base + 48 + lr] = f2bf(vr3 * eff[3] * sc);
                }
        }
        return;
    }

#pragma unroll
    for (int m = 0; m < 4; m++)
#pragma unroll
        for (int n = 0; n < 4; n++) {
            int row = m0 + wr + m * 16 + lg * 4;
            int col = n0 + wc + n * 16 + lr;
            if (EPI == 2) {
                int j = col >> 1;
                int jc = j < 2730 ? j : 2729;
                float su = s_u[jc];
                float sg = s_v[jc] * 32.0f;
#pragma unroll
                for (int i = 0; i < 4; i++) {
                    float own = acc[m][n][i];
                    float oth = __shfl_xor(own, 1, 64);
                    float u = (lr & 1) ? oth : own;
                    float g = (lr & 1) ? own : oth;
                    float uu = u * su;
                    float vv = g * sg;
                    float wv = uu * vv / (1.0f + expf(-vv));
                    if (!(lr & 1))
                        ((short*)Cv)[(size_t)(row + i) * (N >> 1) + j] = f2bf(wv);
                }
            } else {
                void* outp = half ? Cv1 : Cv;
#pragma unroll
                for (int i = 0; i < 4; i++) {
                    if (EPI == 1)
                        ((short*)outp)[(size_t)(row + i) * N + col] = f2bf(acc[m][n][i]);
                    else
                        ((float*)outp)[(size_t)(row + i) * N + col] = acc[m][n][i];
                }
            }
        }
}

// ---------- V transpose: vraw bf16 [4096][1024] -> vt bf16 [B][H][64][2048] ----------
__global__ void k_vtrans(const short* __restrict__ vraw, short* __restrict__ vt) {
    __shared__ short tile[64][72];
    int blk = blockIdx.x;
    int st = blk & 31, h = (blk >> 5) & 15, b = blk >> 9;
    int s0 = st * 64;
    int t = threadIdx.x;
    int sl = t >> 2, c0 = (t & 3) * 16;
    const short* src = vraw + (size_t)(b * 2048 + s0 + sl) * 1024 + h * 64 + c0;
    bf16x8 a0 = *(const bf16x8*)src;
    bf16x8 a1 = *(const bf16x8*)(src + 8);
#pragma unroll
    for (int jj = 0; jj < 8; jj++) { tile[sl][c0 + jj] = a0[jj]; tile[sl][c0 + 8 + jj] = a1[jj]; }
    __syncthreads();
    int hd = t >> 2, sc = (t & 3) * 16;
    bf16x8 p0, p1;
#pragma unroll
    for (int jj = 0; jj < 8; jj++) { p0[jj] = tile[sc + jj][hd]; p1[jj] = tile[sc + 8 + jj][hd]; }
    size_t obase = ((size_t)((b * 16 + h) * 64 + hd)) * 2048 + s0 + sc;
    *(bf16x8*)&vt[obase] = p0;
    *(bf16x8*)&vt[obase + 8] = p1;
}

// ---------- flash attention (causal), static-max softmax, split-K x2, XCD-binned ----------
__launch_bounds__(512)
__global__ void k_attn(const short* __restrict__ qn, const short* __restrict__ kn,
                       const short* __restrict__ vt, short* __restrict__ opart,
                       float* __restrict__ lsump) {
    __shared__ __align__(16) short Ks[2][64 * 64];
    __shared__ __align__(16) short Vs[2][64 * 64];
    __shared__ __align__(16) short Ps[8][32 * 64];
    const int t = threadIdx.x;
    const int w = t >> 6, lane = t & 63;
    const int bid = blockIdx.x;
    const int xcd = bid & 7, kk_ = bid >> 3;
    const int bhg = xcd + ((kk_ >> 4) << 3);
    const int xi = kk_ & 15;
    const int qb = 7 - (xi >> 1), hf = xi & 1;
    const int h = bhg & 15, b = bhg >> 4;
    const int bh = b * 16 + h;
    const int qw = qb * 256 + w * 32;
    const int lr = lane & 15, lg = lane >> 4;
    const short* Qb = qn + (size_t)bh * 2048 * 64;
    const short* Kb = kn + (size_t)bh * 2048 * 64;
    const short* Vb = vt + (size_t)bh * 64 * 2048;
    char* pwc = (char*)&Ps[w][0];

    bf16x8 qf[2][2];
#pragma unroll
    for (int mi = 0; mi < 2; mi++)
#pragma unroll
        for (int kk = 0; kk < 2; kk++)
            qf[mi][kk] = *(const bf16x8*)&Qb[(size_t)(qw + mi * 16 + lr) * 64 + kk * 32 + lg * 8];

    f32x4 oacc[2][4];
#pragma unroll
    for (int mi = 0; mi < 2; mi++)
#pragma unroll
        for (int ct = 0; ct < 4; ct++) oacc[mi][ct] = (f32x4){0.f, 0.f, 0.f, 0.f};
    float psum[2][4];
#pragma unroll
    for (int mi = 0; mi < 2; mi++)
#pragma unroll
        for (int i = 0; i < 4; i++) psum[mi][i] = 0.0f;

    const int ktn = 2 * qb + 2;
    const int kt0 = hf * ktn, kt1 = kt0 + ktn;

#define STAGE_KV(bi, kbase)                                                          \
    {                                                                                \
        int row = w * 8 + (lane >> 3);                                               \
        int scol = (lane & 7) ^ (row & 7);                                           \
        gload16(Kb + (size_t)((kbase) + row) * 64 + scol * 8,                        \
                &Ks[bi][(w * 8) * 64]);                                              \
        gload16(Vb + (size_t)row * 2048 + (kbase) + scol * 8,                        \
                &Vs[bi][(w * 8) * 64]);                                              \
    }

    STAGE_KV(0, kt0 << 6);

    for (int kt = kt0; kt < kt1; kt++) {
        const int kbase = kt << 6;
        const int cur = (kt - kt0) & 1;
        __syncthreads();
        if (kt + 1 < kt1) STAGE_KV(cur ^ 1, (kt + 1) << 6);

        bf16x8 kf[4][2];
#pragma unroll
        for (int ni = 0; ni < 4; ni++)
#pragma unroll
            for (int kk = 0; kk < 2; kk++) {
                int row = ni * 16 + lr;
                kf[ni][kk] = *(const bf16x8*)&Ks[cur][row * 64 + (((kk * 4 + lg) ^ (row & 7)) << 3)];
            }
        f32x4 sv[2][4];
#pragma unroll
        for (int mi = 0; mi < 2; mi++)
#pragma unroll
            for (int ni = 0; ni < 4; ni++) {
                f32x4 s = (f32x4){0.f, 0.f, 0.f, 0.f};
                s = mfma16(qf[mi][0], kf[ni][0], s);
                s = mfma16(qf[mi][1], kf[ni][1], s);
                sv[mi][ni] = s;
            }
        if (kbase + 63 > qw) {
#pragma unroll
            for (int mi = 0; mi < 2; mi++)
#pragma unroll
                for (int ni = 0; ni < 4; ni++)
#pragma unroll
                    for (int i = 0; i < 4; i++) {
                        int qg = qw + mi * 16 + lg * 4 + i;
                        int kg = kbase + ni * 16 + lr;
                        if (kg > qg) sv[mi][ni][i] = -3.0e38f;
                    }
        }
#pragma unroll
        for (int mi = 0; mi < 2; mi++) {
#pragma unroll
            for (int ni = 0; ni < 4; ni++)
#pragma unroll
                for (int i = 0; i < 4; i++) {
                    float p = exp2f((sv[mi][ni][i] - 9.0f) * 1.44269504f);
                    sv[mi][ni][i] = p;
                    psum[mi][i] += p;
                }
#pragma unroll
            for (int ni = 0; ni < 4; ni++)
#pragma unroll
                for (int i = 0; i < 4; i++) {
                    int row = mi * 16 + lg * 4 + i;
                    int col = ni * 16 + lr;
                    unsigned off = (unsigned)(row * 128 + col * 2) ^ ((unsigned)(row & 7) << 4);
                    *(short*)(pwc + off) = f2bf(sv[mi][ni][i]);
                }
        }
        bf16x8 pa[2][2];
#pragma unroll
        for (int mi = 0; mi < 2; mi++)
#pragma unroll
            for (int kk = 0; kk < 2; kk++) {
                int row = mi * 16 + lr;
                unsigned off = (unsigned)(row * 128 + kk * 64 + lg * 16) ^ ((unsigned)(row & 7) << 4);
                pa[mi][kk] = *(const bf16x8*)(pwc + off);
            }
        bf16x8 vf[4][2];
#pragma unroll
        for (int ct = 0; ct < 4; ct++)
#pragma unroll
            for (int kk = 0; kk < 2; kk++) {
                int row = ct * 16 + lr;
                vf[ct][kk] = *(const bf16x8*)&Vs[cur][row * 64 + (((kk * 4 + lg) ^ (row & 7)) << 3)];
            }
#pragma unroll
        for (int mi = 0; mi < 2; mi++)
#pragma unroll
            for (int ct = 0; ct < 4; ct++) {
                oacc[mi][ct] = mfma16(pa[mi][0], vf[ct][0], oacc[mi][ct]);
                oacc[mi][ct] = mfma16(pa[mi][1], vf[ct][1], oacc[mi][ct]);
            }
    }
#undef STAGE_KV

#pragma unroll
    for (int o = 1; o < 16; o <<= 1)
#pragma unroll
        for (int mi = 0; mi < 2; mi++)
#pragma unroll
            for (int i = 0; i < 4; i++)
                psum[mi][i] += __shfl_xor(psum[mi][i], o, 64);

    short* aob = opart + (size_t)hf * 4096 * 1024 + ((size_t)(b * 2048 + qw) * 1024) + h * 64;
#pragma unroll
    for (int mi = 0; mi < 2; mi++)
#pragma unroll
        for (int ct = 0; ct < 4; ct++)
#pragma unroll
            for (int i = 0; i < 4; i++) {
                int q = mi * 16 + lg * 4 + i;
                aob[(size_t)q * 1024 + ct * 16 + lr] = f2bf(oacc[mi][ct][i]);
            }
    if (lr == 0) {
#pragma unroll
        for (int mi = 0; mi < 2; mi++)
#pragma unroll
            for (int i = 0; i < 4; i++)
                lsump[hf * 65536 + bh * 2048 + qw + mi * 16 + lg * 4 + i] = psum[mi][i];
    }
}

// ---------- combine split-K partials: ao = (O0+O1)/(l0+l1), bf16 ----------
__global__ void k_comb(const short* __restrict__ op, const float* __restrict__ ls,
                       short* __restrict__ ao) {
    int i = (blockIdx.x * 256 + threadIdx.x) * 4;
    int row = i >> 10, col = i & 1023;
    int idx = ((row >> 11) * 16 + (col >> 6)) * 2048 + (row & 2047);
    float rl = 1.0f / (ls[idx] + ls[65536 + idx]);
    short4 a = *(const short4*)(op + i);
    short4 c = *(const short4*)(op + 4194304 + i);
    short4 o;
    o.x = f2bf((bf2f(a.x) + bf2f(c.x)) * rl);
    o.y = f2bf((bf2f(a.y) + bf2f(c.y)) * rl);
    o.z = f2bf((bf2f(a.z) + bf2f(c.z)) * rl);
    o.w = f2bf((bf2f(a.w) + bf2f(c.w)) * rl);
    *(short4*)(ao + i) = o;
}

// ---------- residual + double cosine_norm; pre = pre0 + pre1 ----------
// PM: 1 = two f32 partials, 2 = two bf16 partials. base/outf may alias.
template <int PM>
__global__ void k_resnorm(const float* base, const void* __restrict__ pre0v,
                          const void* __restrict__ pre1v,
                          const float* __restrict__ alpha, float* outf,
                          short* __restrict__ outb) {
    __shared__ float red1[4], red2[4];
    int row = blockIdx.x;
    int t = threadIdx.x;
    int w = t >> 6;
    float4 p;
    if (PM == 1) {
        float4 a = *(const float4*)((const float*)pre0v + (size_t)row * 1024 + t * 4);
        float4 c = *(const float4*)((const float*)pre1v + (size_t)row * 1024 + t * 4);
        p.x = a.x + c.x; p.y = a.y + c.y; p.z = a.z + c.z; p.w = a.w + c.w;
    } else {
        short4 a = *(const short4*)((const short*)pre0v + (size_t)row * 1024 + t * 4);
        short4 c = *(const short4*)((const short*)pre1v + (size_t)row * 1024 + t * 4);
        p.x = bf2f(a.x) + bf2f(c.x); p.y = bf2f(a.y) + bf2f(c.y);
        p.z = bf2f(a.z) + bf2f(c.z); p.w = bf2f(a.w) + bf2f(c.w);
    }
    float ss = p.x * p.x + p.y * p.y + p.z * p.z + p.w * p.w;
#pragma unroll
    for (int o = 1; o < 64; o <<= 1) ss += __shfl_xor(ss, o, 64);
    if ((t & 63) == 0) red1[w] = ss;
    __syncthreads();
    float inv1 = 1.0f / fmaxf(sqrtf(red1[0] + red1[1] + red1[2] + red1[3]), 1e-6f);
    const float4 bx = *(const float4*)(base + (size_t)row * 1024 + t * 4);
    const float4 av = *(const float4*)(alpha + t * 4);
    float4 tm;
    tm.x = bx.x + av.x * (p.x * inv1 - bx.x);
    tm.y = bx.y + av.y * (p.y * inv1 - bx.y);
    tm.z = bx.z + av.z * (p.z * inv1 - bx.z);
    tm.w = bx.w + av.w * (p.w * inv1 - bx.w);
    float ss2 = tm.x * tm.x + tm.y * tm.y + tm.z * tm.z + tm.w * tm.w;
#pragma unroll
    for (int o = 1; o < 64; o <<= 1) ss2 += __shfl_xor(ss2, o, 64);
    if ((t & 63) == 0) red2[w] = ss2;
    __syncthreads();
    float inv2 = 1.0f / fmaxf(sqrtf(red2[0] + red2[1] + red2[2] + red2[3]), 1e-6f);
    float4 hv;
    hv.x = tm.x * inv2; hv.y = tm.y * inv2; hv.z = tm.z * inv2; hv.w = tm.w * inv2;
    if (outf) *(float4*)(outf + (size_t)row * 1024 + t * 4) = hv;
    if (outb) {
        short4 o4;
        o4.x = f2bf(hv.x); o4.y = f2bf(hv.y); o4.z = f2bf(hv.z); o4.w = f2bf(hv.w);
        *(short4*)(outb + (size_t)row * 1024 + t * 4) = o4;
    }
}

// ---------- launch ----------
// Workspace (lifetime-overlaid, peak 76,152,832 B = known-safe):
//  [0, 25821184)  weights bf16^T + rope tables                       (whole launch)
//  25821184  xbf(cvt->qkv) -> vt(vtrans->attn) -> h1bf(rn1->swiglu)            8 MB
//  34209792  qn(qkv->attn) -> ao(comb->wo) -> wmlp(swiglu->down, 22.5MB)
//  42598400  kn(qkv->attn) -> hA0 f32(wo->rn1, 16MB: ..59375616)
//  50987008  vraw(qkv->vtrans) -> lsum(attn->comb, 0.5MB)
//  59375616  opart[2] bf16 16MB(attn->comb) -> hA1 f32 16MB(wo->rn1, ..75890688)
//            -> hM0 bf16 8MB(down->rn2)
//  67764224  hM1 bf16 8MB(down->rn2, ..76152832)
extern "C" void kernel_launch(void* const* d_in, const int* in_sizes, int n_in,
                              void* d_out, int out_size, void* d_ws, size_t ws_size,
                              hipStream_t stream) {
    (void)in_sizes; (void)n_in; (void)out_size; (void)ws_size;
    const float* x   = (const float*)d_in[0];
    const float* Wq  = (const float*)d_in[1];
    const float* Wk  = (const float*)d_in[2];
    const float* Wv  = (const float*)d_in[3];
    const float* Wo  = (const float*)d_in[4];
    const float* sqk = (const float*)d_in[5];
    const float* aA  = (const float*)d_in[6];
    const float* Wup = (const float*)d_in[7];
    const float* Wg  = (const float*)d_in[8];
    const float* Wd  = (const float*)d_in[9];
    const float* su  = (const float*)d_in[10];
    const float* sv  = (const float*)d_in[11];
    const float* aM  = (const float*)d_in[12];

    char* ws = (char*)d_ws;
    short* wqkvT  = (short*)(ws + 0);          // [3072][1024]
    short* woT    = (short*)(ws + 6291456);    // [1024][1024]
    short* wugT   = (short*)(ws + 8388608);    // [5504][1024] interleaved up/gate
    short* wdownT = (short*)(ws + 19660800);   // [1024][2752]
    float* cost   = (float*)(ws + 25296896);
    float* sint   = (float*)(ws + 25559040);
    short* xbf    = (short*)(ws + 25821184);
    short* qn     = (short*)(ws + 34209792);
    short* kn     = (short*)(ws + 42598400);
    short* vraw   = (short*)(ws + 50987008);   // [4096][1024] bf16
    short* vt     = (short*)(ws + 25821184);   // reuse xbf
    short* opart  = (short*)(ws + 59375616);   // [2][4096][1024] bf16
    float* lsum   = (float*)(ws + 50987008);   // reuse vraw (dead after vtrans)
    short* ao     = (short*)(ws + 34209792);   // reuse qn
    float* hA0    = (float*)(ws + 42598400);   // reuse kn, 16MB
    float* hA1    = (float*)(ws + 59375616);   // reuse opart, 16MB
    float* h1f    = (float*)d_out;
    short* h1bf   = (short*)(ws + 25821184);   // reuse vt
    short* wmlp   = (short*)(ws + 34209792);   // [4096][2752] bf16, 22.5MB
    short* hM0    = (short*)(ws + 59375616);   // bf16 8MB
    short* hM1    = (short*)(ws + 67764224);   // bf16 8MB

    k_cvt_bf16<<<4096, 256, 0, stream>>>(x, xbf, 4194304);
    k_transpose_cvt<<<dim3(32, 32), 256, 0, stream>>>(Wq, wqkvT,           1024, 1024, 1024, 1024, 1, 0);
    k_transpose_cvt<<<dim3(32, 32), 256, 0, stream>>>(Wk, wqkvT + 1048576, 1024, 1024, 1024, 1024, 1, 0);
    k_transpose_cvt<<<dim3(32, 32), 256, 0, stream>>>(Wv, wqkvT + 2097152, 1024, 1024, 1024, 1024, 1, 0);
    k_transpose_cvt<<<dim3(32, 32), 256, 0, stream>>>(Wo, woT,             1024, 1024, 1024, 1024, 1, 0);
    k_transpose_cvt<<<dim3(86, 32), 256, 0, stream>>>(Wup, wugT, 1024, 2730, 1024, 2752, 2, 0);
    k_transpose_cvt<<<dim3(86, 32), 256, 0, stream>>>(Wg,  wugT, 1024, 2730, 1024, 2752, 2, 1);
    k_transpose_cvt<<<dim3(32, 86), 256, 0, stream>>>(Wd,  wdownT, 2730, 1024, 2752, 1024, 1, 0);
    k_freqs<<<256, 256, 0, stream>>>(cost, sint);

    // QKV GEMM with fused rope + cosine-norm epilogue
    k_gemm128<3><<<768, 256, 0, stream>>>(xbf, wqkvT, nullptr, nullptr, 4096, 3072, 1024,
                                          32, 1, nullptr, nullptr, cost, sint, sqk, qn, kn, vraw);
    k_vtrans<<<1024, 256, 0, stream>>>(vraw, vt);
    k_attn<<<512, 512, 0, stream>>>(qn, kn, vt, opart, lsum);
    k_comb<<<4096, 256, 0, stream>>>(opart, lsum, ao);
    // Wo: split-K x2, f32 partials
    k_gemm128<0><<<512, 256, 0, stream>>>(ao, woT, hA0, hA1, 4096, 1024, 1024,
                                          16, 2, nullptr, nullptr, nullptr, nullptr, nullptr, nullptr, nullptr, nullptr);
    k_resnorm<1><<<4096, 256, 0, stream>>>(x, hA0, hA1, aA, h1f, h1bf);
    // up+gate fused SwiGLU
    k_gemm128<2><<<1376, 256, 0, stream>>>(h1bf, wugT, wmlp, nullptr, 4096, 5504, 1024,
                                           32, 1, su, sv, nullptr, nullptr, nullptr, nullptr, nullptr, nullptr);
    // down: split-K x2, bf16 partials
    k_gemm128<1><<<512, 256, 0, stream>>>(wmlp, wdownT, hM0, hM1, 4096, 1024, 2752,
                                          43, 2, nullptr, nullptr, nullptr, nullptr, nullptr, nullptr, nullptr, nullptr);
    k_resnorm<2><<<4096, 256, 0, stream>>>(h1f, hM0, hM1, aM, (float*)d_out, (short*)nullptr);
}